// Round 3
// baseline (446.183 us; speedup 1.0000x reference)
//
#include <hip/hip_runtime.h>
#include <math.h>

#define HW 16384
#define W_ 128

typedef __bf16 bf16x8 __attribute__((ext_vector_type(8)));
typedef float f32x4 __attribute__((ext_vector_type(4)));

__device__ __forceinline__ ushort f2bf(float f) {
    uint u = __builtin_bit_cast(uint, f);
    u += 0x7FFFu + ((u >> 16) & 1u);   // round-to-nearest-even
    return (ushort)(u >> 16);
}

union FragU { ushort4 h[2]; bf16x8 v; };

// ---------------------------------------------------------------------------
// 1x1 conv as bf16-MFMA GEMM + fused GroupNorm partial stats.
// out[n][o][p] = bias[o] + sum_c w[o][c]*in[n][c][p]
// block tile 128 o x 128 p, 4 waves (2x2), wave tile 64x64, K-step 32.
// Epilogue: per-group (sum,sumsq) via LDS atomics -> global atomicAdd.
// ---------------------------------------------------------------------------
template<int IC, int LOG2CG>
__global__ __launch_bounds__(256) void conv1x1_mfma(
    const float* __restrict__ in, const float* __restrict__ w,
    const float* __restrict__ bias, float* __restrict__ out,
    float* __restrict__ sums, long in_nstride, long out_nstride)
{
    __shared__ ushort A_s[128][34];
    __shared__ ushort B_s[128][34];
    __shared__ float gsum[32][2];
    const int tid = threadIdx.x;
    const int lane = tid & 63;
    const int wave = tid >> 6;
    const int woM = (wave >> 1) << 6;
    const int wpN = (wave & 1) << 6;
    const int lr = lane & 15;
    const int kg = (lane >> 4) << 2;
    const int n = blockIdx.z;
    const int obase = blockIdx.y << 7;
    const int pbase = blockIdx.x << 7;
    const float* inn = in + (long)n * in_nstride;

    if (tid < 32) { gsum[tid][0] = 0.f; gsum[tid][1] = 0.f; }

    f32x4 acc[4][4] = {};

    for (int c0 = 0; c0 < IC; c0 += 32) {
#pragma unroll
        for (int r = 0; r < 4; ++r) {
            int idx4 = (r << 8) + tid;
            int o = idx4 >> 3, kq = idx4 & 7;
            float4 wv = *(const float4*)&w[(long)(obase + o) * IC + c0 + (kq << 2)];
            ushort4 hb;
            hb.x = f2bf(wv.x); hb.y = f2bf(wv.y); hb.z = f2bf(wv.z); hb.w = f2bf(wv.w);
            *(ushort4*)&A_s[o][kq << 2] = hb;
        }
#pragma unroll
        for (int r = 0; r < 16; ++r) {
            int idx = (r << 8) + tid;
            int c = idx >> 7, p = idx & 127;
            B_s[p][c] = f2bf(inn[(long)(c0 + c) * HW + pbase + p]);
        }
        __syncthreads();

        FragU af[4], bfr[4];
#pragma unroll
        for (int mo = 0; mo < 4; ++mo) {
            const ushort* base = &A_s[woM + (mo << 4) + lr][0];
            af[mo].h[0] = *(const ushort4*)(base + kg);
            af[mo].h[1] = *(const ushort4*)(base + 16 + kg);
        }
#pragma unroll
        for (int po = 0; po < 4; ++po) {
            const ushort* base = &B_s[wpN + (po << 4) + lr][0];
            bfr[po].h[0] = *(const ushort4*)(base + kg);
            bfr[po].h[1] = *(const ushort4*)(base + 16 + kg);
        }
#pragma unroll
        for (int mo = 0; mo < 4; ++mo)
#pragma unroll
            for (int po = 0; po < 4; ++po)
                acc[mo][po] = __builtin_amdgcn_mfma_f32_16x16x32_bf16(
                    af[mo].v, bfr[po].v, acc[mo][po], 0, 0, 0);
        __syncthreads();
    }

    // add bias into acc
    if (bias) {
#pragma unroll
        for (int mo = 0; mo < 4; ++mo)
#pragma unroll
            for (int r = 0; r < 4; ++r) {
                float b = bias[obase + woM + (mo << 4) + kg + r];
#pragma unroll
                for (int po = 0; po < 4; ++po) acc[mo][po][r] += b;
            }
    }

    // store
    float* outn = out + (long)n * out_nstride;
#pragma unroll
    for (int mo = 0; mo < 4; ++mo) {
        int orow0 = obase + woM + (mo << 4) + kg;
#pragma unroll
        for (int po = 0; po < 4; ++po) {
            int p = pbase + wpN + (po << 4) + lr;
#pragma unroll
            for (int r = 0; r < 4; ++r)
                outn[(long)(orow0 + r) * HW + p] = acc[mo][po][r];
        }
    }

    // fused GN partial stats: each (thread,mo) covers one group (CG>=4)
#pragma unroll
    for (int mo = 0; mo < 4; ++mo) {
        float s = 0.f, ss = 0.f;
#pragma unroll
        for (int po = 0; po < 4; ++po)
#pragma unroll
            for (int r = 0; r < 4; ++r) {
                float v = acc[mo][po][r];
                s += v; ss += v * v;
            }
        int gt = (woM + (mo << 4) + kg) >> LOG2CG;
        atomicAdd(&gsum[gt][0], s);
        atomicAdd(&gsum[gt][1], ss);
    }
    __syncthreads();
    if (tid < (128 >> LOG2CG)) {
        int g = (obase >> LOG2CG) + tid;
        atomicAdd(&sums[2 * (n * 32 + g)],     gsum[tid][0]);
        atomicAdd(&sums[2 * (n * 32 + g) + 1], gsum[tid][1]);
    }
}

// ---------------------------------------------------------------------------
__global__ void gn_final_kernel(const float* __restrict__ sums,
                                float* __restrict__ mu, float* __restrict__ rstd,
                                float cinv)
{
    int i = threadIdx.x;
    if (i < 128) {
        float m = sums[2 * i] * cinv;
        float var = sums[2 * i + 1] * cinv - m * m;
        mu[i] = m;
        rstd[i] = rsqrtf(var + 1e-5f);
    }
}

__global__ __launch_bounds__(256) void gn_apply_kernel(
    float* __restrict__ y, const float* __restrict__ mu, const float* __restrict__ rstd,
    const float* __restrict__ gamma, const float* __restrict__ beta,
    long nstride, int CG, int G)
{
    const int n = blockIdx.z, c = blockIdx.y;
    const int ng = n * G + c / CG;
    const float a = rstd[ng] * gamma[c];
    const float b = beta[c] - mu[ng] * a;
    float* p = y + (long)n * nstride + (long)c * HW + (blockIdx.x << 10) + (threadIdx.x << 2);
    float4 v = *(const float4*)p;
    v.x = fmaxf(v.x * a + b, 0.f);
    v.y = fmaxf(v.y * a + b, 0.f);
    v.z = fmaxf(v.z * a + b, 0.f);
    v.w = fmaxf(v.w * a + b, 0.f);
    *(float4*)p = v;
}

__global__ __launch_bounds__(256) void gn_final_apply_kernel(
    float* __restrict__ y, const float* __restrict__ x,
    const float* __restrict__ mu, const float* __restrict__ rstd,
    const float* __restrict__ gamma, const float* __restrict__ beta,
    long nstride, int CG, int G)
{
    const int n = blockIdx.z, c = blockIdx.y;
    const int ng = n * G + c / CG;
    const float a = rstd[ng] * gamma[c];
    const float b = beta[c] - mu[ng] * a;
    long off = (long)n * nstride + (long)c * HW + (blockIdx.x << 10) + (threadIdx.x << 2);
    float4 v = *(const float4*)&y[off];
    float4 xv = *(const float4*)&x[off];
    v.x = fmaxf(v.x * a + b, 0.f) + xv.x;
    v.y = fmaxf(v.y * a + b, 0.f) + xv.y;
    v.z = fmaxf(v.z * a + b, 0.f) + xv.z;
    v.w = fmaxf(v.w * a + b, 0.f) + xv.w;
    *(float4*)&y[off] = v;
}

// ---------------------------------------------------------------------------
// cata pass 1: 3x3 conv -> 9 logits, 4 vertical px/thread, 16-ch chunks.
// tile 8 rows x 128 cols, halo 10x130 in LDS. atomicAdd into logits.
// grid (16 row-tiles, 4 n, 8 chunks), block 256.
// ---------------------------------------------------------------------------
#define RT 8
__global__ __launch_bounds__(256) void cata_logits_kernel(
    const float* __restrict__ xd, const float* __restrict__ wc,
    float* __restrict__ logits)
{
    __shared__ float wcs[9 * 16 * 9];          // 5184 B
    __shared__ float xs[RT + 2][130];          // 5200 B
    const int tid = threadIdx.x;
    const int r0 = blockIdx.x * RT;
    const int n = blockIdx.y;
    const int c0 = blockIdx.z << 4;
    const int qq = tid >> 7;                   // 0/1: row-quad
    const int w = tid & 127;
    for (int i = tid; i < 9 * 16 * 9; i += 256) {
        int k = i / 144, rem = i % 144;
        wcs[i] = wc[k * 1152 + c0 * 9 + rem];
    }
    const float* xn = xd + (long)n * 256 * HW;
    float lg[4][9] = {};
    for (int cc = 0; cc < 16; ++cc) {
        __syncthreads();
        const float* xc = xn + (long)(c0 + cc) * HW;
        for (int i = tid; i < (RT + 2) * 130; i += 256) {
            int rr = i / 130, cl = i % 130;
            int gr = r0 - 1 + rr, gc = cl - 1;
            xs[rr][cl] = (gr >= 0 && gr < 128 && gc >= 0 && gc < 128)
                         ? xc[gr * W_ + gc] : 0.f;
        }
        __syncthreads();
        float nb[6][3];
#pragma unroll
        for (int rr = 0; rr < 6; ++rr)
#pragma unroll
            for (int dj = 0; dj < 3; ++dj)
                nb[rr][dj] = xs[(qq << 2) + rr][w + dj];
#pragma unroll
        for (int k = 0; k < 9; ++k) {
            const float* wkp = &wcs[(k * 16 + cc) * 9];
            float wk[9];
#pragma unroll
            for (int t = 0; t < 9; ++t) wk[t] = wkp[t];
#pragma unroll
            for (int i = 0; i < 4; ++i) {
                float s = lg[i][k];
#pragma unroll
                for (int di = 0; di < 3; ++di)
#pragma unroll
                    for (int dj = 0; dj < 3; ++dj)
                        s += wk[di * 3 + dj] * nb[i + di][dj];
                lg[i][k] = s;
            }
        }
    }
    float* lgn = logits + (long)n * 9 * HW;
#pragma unroll
    for (int i = 0; i < 4; ++i) {
        int p = (r0 + (qq << 2) + i) * W_ + w;
#pragma unroll
        for (int k = 0; k < 9; ++k)
            atomicAdd(&lgn[(long)k * HW + p], lg[i][k]);
    }
}

// ---------------------------------------------------------------------------
// cata pass 2: softmax over 9 logits + weighted 3x3 sum, same tiling.
// out1 -> cat channels 128..255.
// ---------------------------------------------------------------------------
__global__ __launch_bounds__(256) void cata_wsum_kernel(
    float* __restrict__ cat, const float* __restrict__ logits)
{
    __shared__ float xs[RT + 2][130];
    const int tid = threadIdx.x;
    const int r0 = blockIdx.x * RT;
    const int n = blockIdx.y;
    const int c0 = blockIdx.z << 4;
    const int qq = tid >> 7;
    const int w = tid & 127;
    const float* lgn = logits + (long)n * 9 * HW;
    float filt[4][9];
#pragma unroll
    for (int i = 0; i < 4; ++i) {
        int p = (r0 + (qq << 2) + i) * W_ + w;
        float v[9], m = -1e30f;
#pragma unroll
        for (int k = 0; k < 9; ++k) {
            v[k] = lgn[(long)k * HW + p];
            m = fmaxf(m, v[k]);
        }
        float s = 0.f;
#pragma unroll
        for (int k = 0; k < 9; ++k) { v[k] = __expf(v[k] - m); s += v[k]; }
        float inv = 1.f / s;
#pragma unroll
        for (int k = 0; k < 9; ++k) filt[i][k] = v[k] * inv;
    }
    const float* xn = cat + (long)n * 256 * HW;
    float* o1 = cat + (long)n * 256 * HW + 128L * HW;
    for (int cc = 0; cc < 16; ++cc) {
        __syncthreads();
        const float* xc = xn + (long)(c0 + cc) * HW;
        for (int i = tid; i < (RT + 2) * 130; i += 256) {
            int rr = i / 130, cl = i % 130;
            int gr = r0 - 1 + rr, gc = cl - 1;
            xs[rr][cl] = (gr >= 0 && gr < 128 && gc >= 0 && gc < 128)
                         ? xc[gr * W_ + gc] : 0.f;
        }
        __syncthreads();
        float nb[6][3];
#pragma unroll
        for (int rr = 0; rr < 6; ++rr)
#pragma unroll
            for (int dj = 0; dj < 3; ++dj)
                nb[rr][dj] = xs[(qq << 2) + rr][w + dj];
#pragma unroll
        for (int i = 0; i < 4; ++i) {
            float s = 0.f;
#pragma unroll
            for (int di = 0; di < 3; ++di)
#pragma unroll
                for (int dj = 0; dj < 3; ++dj)
                    s += filt[i][di * 3 + dj] * nb[i + di][dj];
            o1[(long)(c0 + cc) * HW + (r0 + (qq << 2) + i) * W_ + w] = s;
        }
    }
}

// ---------------------------------------------------------------------------
extern "C" void kernel_launch(void* const* d_in, const int* in_sizes, int n_in,
                              void* d_out, int out_size, void* d_ws, size_t ws_size,
                              hipStream_t stream)
{
    const float* x   = (const float*)d_in[0];
    const float* w1  = (const float*)d_in[1];
    const float* g1  = (const float*)d_in[2];
    const float* b1  = (const float*)d_in[3];
    const float* wc  = (const float*)d_in[4];
    const float* w2  = (const float*)d_in[5];
    const float* bw2 = (const float*)d_in[6];
    const float* g2  = (const float*)d_in[7];
    const float* b2  = (const float*)d_in[8];
    const float* w3  = (const float*)d_in[9];
    const float* bw3 = (const float*)d_in[10];
    const float* g3  = (const float*)d_in[11];
    const float* b3  = (const float*)d_in[12];
    float* out = (float*)d_out;

    float* cat    = (float*)d_ws;                     // [4][256][HW] 64MB
    float* h2     = cat + (long)4 * 256 * HW;         // [4][128][HW] 32MB
    float* sums1  = h2 + (long)4 * 128 * HW;          // 256
    float* sums2  = sums1 + 256;                      // 256
    float* sums3  = sums2 + 256;                      // 256
    float* mu     = sums3 + 256;                      // 128
    float* rstd   = mu + 128;                         // 128
    float* logits = rstd + 128;                       // [4][9][HW] 2.36MB

    const long catN = 256L * HW, hN = 128L * HW, xN = 512L * HW;

    hipMemsetAsync(sums1, 0, 768 * sizeof(float), stream);

    // scale1: 1x1 conv (bf16 MFMA, fused stats) -> GN -> ReLU
    conv1x1_mfma<512, 2><<<dim3(128, 1, 4), 256, 0, stream>>>(x, w1, nullptr, cat, sums1, xN, catN);
    gn_final_kernel<<<1, 128, 0, stream>>>(sums1, mu, rstd, 1.f / 65536.f);
    gn_apply_kernel<<<dim3(16, 128, 4), 256, 0, stream>>>(cat, mu, rstd, g1, b1, catN, 4, 32);

    // cata
    hipMemsetAsync(logits, 0, (size_t)4 * 9 * HW * sizeof(float), stream);
    cata_logits_kernel<<<dim3(16, 4, 8), 256, 0, stream>>>(cat, wc, logits);
    cata_wsum_kernel<<<dim3(16, 4, 8), 256, 0, stream>>>(cat, logits);

    // scale2
    conv1x1_mfma<256, 2><<<dim3(128, 1, 4), 256, 0, stream>>>(cat, w2, bw2, h2, sums2, catN, hN);
    gn_final_kernel<<<1, 128, 0, stream>>>(sums2, mu, rstd, 1.f / 65536.f);
    gn_apply_kernel<<<dim3(16, 128, 4), 256, 0, stream>>>(h2, mu, rstd, g2, b2, hN, 4, 32);

    // scale3 + residual
    conv1x1_mfma<128, 4><<<dim3(128, 4, 4), 256, 0, stream>>>(h2, w3, bw3, out, sums3, hN, xN);
    gn_final_kernel<<<1, 128, 0, stream>>>(sums3, mu, rstd, 1.f / 262144.f);
    gn_final_apply_kernel<<<dim3(16, 512, 4), 256, 0, stream>>>(out, x, mu, rstd, g3, b3, xN, 16, 32);
}

// Round 4
// 298.455 us; speedup vs baseline: 1.4950x; 1.4950x over previous
//
#include <hip/hip_runtime.h>
#include <math.h>

#define HW 16384
#define W_ 128

typedef __bf16 bf16x8 __attribute__((ext_vector_type(8)));
typedef float f32x4 __attribute__((ext_vector_type(4)));

__device__ __forceinline__ ushort f2bf(float f) {
    uint u = __builtin_bit_cast(uint, f);
    u += 0x7FFFu + ((u >> 16) & 1u);   // round-to-nearest-even
    return (ushort)(u >> 16);
}

union FragU { ushort u[8]; ushort4 h[2]; bf16x8 v; };

// ---------------------------------------------------------------------------
// 1x1 conv as bf16-MFMA GEMM + fused GN partial stats + optional fused
// input-GN-apply (v = relu(a*v+b) during staging).
// block tile 128 o x 128 p, 4 waves (2x2), wave tile 64x64, K-step 32.
// A_s[o][k] (pad 36); B_s[c][p] natural layout (pad 132), transpose-on-read.
// Register-prefetch pipeline on both A and B staging loads.
// ---------------------------------------------------------------------------
template<int IC, int LOG2CG, bool NORM_IN>
__global__ __launch_bounds__(256) void conv1x1_mfma(
    const float* __restrict__ in, const float2* __restrict__ ab,
    const float* __restrict__ w, const float* __restrict__ bias,
    float* __restrict__ out, float* __restrict__ sums,
    long in_nstride, long out_nstride)
{
    __shared__ ushort A_s[128][36];
    __shared__ ushort B_s[32][132];
    __shared__ float gsum[32][2];
    const int tid = threadIdx.x;
    const int lane = tid & 63;
    const int wave = tid >> 6;
    const int woM = (wave >> 1) << 6;
    const int wpN = (wave & 1) << 6;
    const int lr = lane & 15;
    const int kg = (lane >> 4) << 2;
    const int n = blockIdx.z;
    const int obase = blockIdx.y << 7;
    const int pbase = blockIdx.x << 7;
    const float* inn = in + (long)n * in_nstride;

    if (tid < 32) { gsum[tid][0] = 0.f; gsum[tid][1] = 0.f; }

    f32x4 acc[4][4] = {};
    float4 areg[4], breg[4];
    float2 abreg[4];

    auto issue_loads = [&](int c0) {
#pragma unroll
        for (int r = 0; r < 4; ++r) {
            int idx4 = (r << 8) + tid;
            int o = idx4 >> 3, kq = idx4 & 7;
            areg[r] = *(const float4*)&w[(long)(obase + o) * IC + c0 + (kq << 2)];
        }
#pragma unroll
        for (int r = 0; r < 4; ++r) {
            int idx4 = (r << 8) + tid;
            int c = idx4 >> 5, p4 = (idx4 & 31) << 2;
            breg[r] = *(const float4*)&inn[(long)(c0 + c) * HW + pbase + p4];
            if (NORM_IN) abreg[r] = ab[(long)n * IC + c0 + c];
        }
    };
    auto write_lds = [&]() {
#pragma unroll
        for (int r = 0; r < 4; ++r) {
            int idx4 = (r << 8) + tid;
            int o = idx4 >> 3, kq = idx4 & 7;
            float4 v = areg[r];
            ushort4 h;
            h.x = f2bf(v.x); h.y = f2bf(v.y); h.z = f2bf(v.z); h.w = f2bf(v.w);
            *(ushort4*)&A_s[o][kq << 2] = h;
        }
#pragma unroll
        for (int r = 0; r < 4; ++r) {
            int idx4 = (r << 8) + tid;
            int c = idx4 >> 5, p4 = (idx4 & 31) << 2;
            float4 v = breg[r];
            if (NORM_IN) {
                float a = abreg[r].x, b = abreg[r].y;
                v.x = fmaxf(fmaf(v.x, a, b), 0.f);
                v.y = fmaxf(fmaf(v.y, a, b), 0.f);
                v.z = fmaxf(fmaf(v.z, a, b), 0.f);
                v.w = fmaxf(fmaf(v.w, a, b), 0.f);
            }
            ushort4 h;
            h.x = f2bf(v.x); h.y = f2bf(v.y); h.z = f2bf(v.z); h.w = f2bf(v.w);
            *(ushort4*)&B_s[c][p4] = h;
        }
    };

    issue_loads(0);
    constexpr int NS = IC / 32;
    for (int s = 0; s < NS; ++s) {
        write_lds();
        __syncthreads();
        if (s + 1 < NS) issue_loads((s + 1) << 5);

        FragU af[4];
#pragma unroll
        for (int mo = 0; mo < 4; ++mo) {
            const ushort* base = &A_s[woM + (mo << 4) + lr][0];
            af[mo].h[0] = *(const ushort4*)(base + kg);
            af[mo].h[1] = *(const ushort4*)(base + 16 + kg);
        }
#pragma unroll
        for (int po = 0; po < 4; ++po) {
            FragU bf_;
            int p = wpN + (po << 4) + lr;
#pragma unroll
            for (int j = 0; j < 4; ++j) {
                bf_.u[j]     = B_s[kg + j][p];
                bf_.u[4 + j] = B_s[16 + kg + j][p];
            }
#pragma unroll
            for (int mo = 0; mo < 4; ++mo)
                acc[mo][po] = __builtin_amdgcn_mfma_f32_16x16x32_bf16(
                    af[mo].v, bf_.v, acc[mo][po], 0, 0, 0);
        }
        __syncthreads();
    }

    if (bias) {
#pragma unroll
        for (int mo = 0; mo < 4; ++mo)
#pragma unroll
            for (int r = 0; r < 4; ++r) {
                float b = bias[obase + woM + (mo << 4) + kg + r];
#pragma unroll
                for (int po = 0; po < 4; ++po) acc[mo][po][r] += b;
            }
    }

    float* outn = out + (long)n * out_nstride;
#pragma unroll
    for (int mo = 0; mo < 4; ++mo) {
        int orow0 = obase + woM + (mo << 4) + kg;
#pragma unroll
        for (int po = 0; po < 4; ++po) {
            int p = pbase + wpN + (po << 4) + lr;
#pragma unroll
            for (int r = 0; r < 4; ++r)
                outn[(long)(orow0 + r) * HW + p] = acc[mo][po][r];
        }
    }

    // fused GN partial stats: shfl-reduce 16-lane groups, leaders -> LDS -> global
#pragma unroll
    for (int mo = 0; mo < 4; ++mo) {
        float s = 0.f, ss = 0.f;
#pragma unroll
        for (int po = 0; po < 4; ++po)
#pragma unroll
            for (int r = 0; r < 4; ++r) {
                float v = acc[mo][po][r];
                s += v; ss += v * v;
            }
#pragma unroll
        for (int m = 8; m >= 1; m >>= 1) {
            s  += __shfl_xor(s, m, 64);
            ss += __shfl_xor(ss, m, 64);
        }
        if (lr == 0) {
            int gt = (woM + (mo << 4) + kg) >> LOG2CG;
            atomicAdd(&gsum[gt][0], s);
            atomicAdd(&gsum[gt][1], ss);
        }
    }
    __syncthreads();
    if (tid < (128 >> LOG2CG)) {
        int g = (obase >> LOG2CG) + tid;
        atomicAdd(&sums[2 * (n * 32 + g)],     gsum[tid][0]);
        atomicAdd(&sums[2 * (n * 32 + g) + 1], gsum[tid][1]);
    }
}

// ---------------------------------------------------------------------------
// per-channel GN coefficients: ab[n][c] = (a,b) with y_norm = relu(a*y+b)
// identity (1,0) for c >= norm_c (the out1 half of the concat input).
// ---------------------------------------------------------------------------
__global__ void gn_coef_kernel(const float* __restrict__ sums,
                               const float* __restrict__ gamma,
                               const float* __restrict__ beta,
                               float2* __restrict__ ab,
                               float cinv, int C, int log2cg, int norm_c)
{
    int n = blockIdx.x;
    for (int c = threadIdx.x; c < C; c += blockDim.x) {
        float a = 1.f, b = 0.f;
        if (c < norm_c) {
            int g = c >> log2cg;
            float m = sums[2 * (n * 32 + g)] * cinv;
            float var = sums[2 * (n * 32 + g) + 1] * cinv - m * m;
            float r = rsqrtf(var + 1e-5f);
            a = r * gamma[c];
            b = beta[c] - m * a;
        }
        ab[(long)n * C + c] = make_float2(a, b);
    }
}

__global__ void gn_final_kernel(const float* __restrict__ sums,
                                float* __restrict__ mu, float* __restrict__ rstd,
                                float cinv)
{
    int i = threadIdx.x;
    if (i < 128) {
        float m = sums[2 * i] * cinv;
        float var = sums[2 * i + 1] * cinv - m * m;
        mu[i] = m;
        rstd[i] = rsqrtf(var + 1e-5f);
    }
}

// final: out = relu((y-mu)*rstd*g + b) + x, in place on y(=d_out)
__global__ __launch_bounds__(256) void gn_final_apply_kernel(
    float* __restrict__ y, const float* __restrict__ x,
    const float* __restrict__ mu, const float* __restrict__ rstd,
    const float* __restrict__ gamma, const float* __restrict__ beta,
    long nstride, int CG, int G)
{
    const int n = blockIdx.z, c = blockIdx.y;
    const int ng = n * G + c / CG;
    const float a = rstd[ng] * gamma[c];
    const float b = beta[c] - mu[ng] * a;
    long off = (long)n * nstride + (long)c * HW + (blockIdx.x << 10) + (threadIdx.x << 2);
    float4 v = *(const float4*)&y[off];
    float4 xv = *(const float4*)&x[off];
    v.x = fmaxf(v.x * a + b, 0.f) + xv.x;
    v.y = fmaxf(v.y * a + b, 0.f) + xv.y;
    v.z = fmaxf(v.z * a + b, 0.f) + xv.z;
    v.w = fmaxf(v.w * a + b, 0.f) + xv.w;
    *(float4*)&y[off] = v;
}

// ---------------------------------------------------------------------------
// cata pass 1: 3x3 conv -> 9 logits, reads RAW xd + applies (a,b)+relu on load.
// tile 8 rows x 128 cols, halo 10x130 in LDS, 16-ch chunks, atomics to logits.
// ---------------------------------------------------------------------------
#define RT 8
__global__ __launch_bounds__(256) void cata_logits_kernel(
    const float* __restrict__ xd, const float2* __restrict__ ab,
    const float* __restrict__ wc, float* __restrict__ logits)
{
    __shared__ float wcs[9 * 16 * 9];
    __shared__ float xs[RT + 2][130];
    const int tid = threadIdx.x;
    const int r0 = blockIdx.x * RT;
    const int n = blockIdx.y;
    const int c0 = blockIdx.z << 4;
    const int qq = tid >> 7;
    const int w = tid & 127;
    for (int i = tid; i < 9 * 16 * 9; i += 256) {
        int k = i / 144, rem = i % 144;
        wcs[i] = wc[k * 1152 + c0 * 9 + rem];
    }
    const float* xn = xd + (long)n * 256 * HW;
    float lg[4][9] = {};
    for (int cc = 0; cc < 16; ++cc) {
        __syncthreads();
        const float* xc = xn + (long)(c0 + cc) * HW;
        float2 abv = ab[(long)n * 256 + c0 + cc];
        for (int i = tid; i < (RT + 2) * 130; i += 256) {
            int rr = i / 130, cl = i % 130;
            int gr = r0 - 1 + rr, gc = cl - 1;
            float v = 0.f;
            if (gr >= 0 && gr < 128 && gc >= 0 && gc < 128)
                v = fmaxf(fmaf(xc[gr * W_ + gc], abv.x, abv.y), 0.f);
            xs[rr][cl] = v;
        }
        __syncthreads();
        float nb[6][3];
#pragma unroll
        for (int rr = 0; rr < 6; ++rr)
#pragma unroll
            for (int dj = 0; dj < 3; ++dj)
                nb[rr][dj] = xs[(qq << 2) + rr][w + dj];
#pragma unroll
        for (int k = 0; k < 9; ++k) {
            const float* wkp = &wcs[(k * 16 + cc) * 9];
            float wk[9];
#pragma unroll
            for (int t = 0; t < 9; ++t) wk[t] = wkp[t];
#pragma unroll
            for (int i = 0; i < 4; ++i) {
                float s = lg[i][k];
#pragma unroll
                for (int di = 0; di < 3; ++di)
#pragma unroll
                    for (int dj = 0; dj < 3; ++dj)
                        s += wk[di * 3 + dj] * nb[i + di][dj];
                lg[i][k] = s;
            }
        }
    }
    float* lgn = logits + (long)n * 9 * HW;
#pragma unroll
    for (int i = 0; i < 4; ++i) {
        int p = (r0 + (qq << 2) + i) * W_ + w;
#pragma unroll
        for (int k = 0; k < 9; ++k)
            atomicAdd(&lgn[(long)k * HW + p], lg[i][k]);
    }
}

// ---------------------------------------------------------------------------
// cata pass 2: softmax over 9 logits + weighted 3x3 sum; reads RAW xd +
// applies (a,b)+relu on load; out1 -> cat channels 128..255 (final values).
// ---------------------------------------------------------------------------
__global__ __launch_bounds__(256) void cata_wsum_kernel(
    float* __restrict__ cat, const float2* __restrict__ ab,
    const float* __restrict__ logits)
{
    __shared__ float xs[RT + 2][130];
    const int tid = threadIdx.x;
    const int r0 = blockIdx.x * RT;
    const int n = blockIdx.y;
    const int c0 = blockIdx.z << 4;
    const int qq = tid >> 7;
    const int w = tid & 127;
    const float* lgn = logits + (long)n * 9 * HW;
    float filt[4][9];
#pragma unroll
    for (int i = 0; i < 4; ++i) {
        int p = (r0 + (qq << 2) + i) * W_ + w;
        float v[9], m = -1e30f;
#pragma unroll
        for (int k = 0; k < 9; ++k) {
            v[k] = lgn[(long)k * HW + p];
            m = fmaxf(m, v[k]);
        }
        float s = 0.f;
#pragma unroll
        for (int k = 0; k < 9; ++k) { v[k] = __expf(v[k] - m); s += v[k]; }
        float inv = 1.f / s;
#pragma unroll
        for (int k = 0; k < 9; ++k) filt[i][k] = v[k] * inv;
    }
    const float* xn = cat + (long)n * 256 * HW;
    float* o1 = cat + (long)n * 256 * HW + 128L * HW;
    for (int cc = 0; cc < 16; ++cc) {
        __syncthreads();
        const float* xc = xn + (long)(c0 + cc) * HW;
        float2 abv = ab[(long)n * 256 + c0 + cc];
        for (int i = tid; i < (RT + 2) * 130; i += 256) {
            int rr = i / 130, cl = i % 130;
            int gr = r0 - 1 + rr, gc = cl - 1;
            float v = 0.f;
            if (gr >= 0 && gr < 128 && gc >= 0 && gc < 128)
                v = fmaxf(fmaf(xc[gr * W_ + gc], abv.x, abv.y), 0.f);
            xs[rr][cl] = v;
        }
        __syncthreads();
        float nb[6][3];
#pragma unroll
        for (int rr = 0; rr < 6; ++rr)
#pragma unroll
            for (int dj = 0; dj < 3; ++dj)
                nb[rr][dj] = xs[(qq << 2) + rr][w + dj];
#pragma unroll
        for (int i = 0; i < 4; ++i) {
            float s = 0.f;
#pragma unroll
            for (int di = 0; di < 3; ++di)
#pragma unroll
                for (int dj = 0; dj < 3; ++dj)
                    s += filt[i][di * 3 + dj] * nb[i + di][dj];
            o1[(long)(c0 + cc) * HW + (r0 + (qq << 2) + i) * W_ + w] = s;
        }
    }
}

// ---------------------------------------------------------------------------
extern "C" void kernel_launch(void* const* d_in, const int* in_sizes, int n_in,
                              void* d_out, int out_size, void* d_ws, size_t ws_size,
                              hipStream_t stream)
{
    const float* x   = (const float*)d_in[0];
    const float* w1  = (const float*)d_in[1];
    const float* g1  = (const float*)d_in[2];
    const float* b1  = (const float*)d_in[3];
    const float* wc  = (const float*)d_in[4];
    const float* w2  = (const float*)d_in[5];
    const float* bw2 = (const float*)d_in[6];
    const float* g2  = (const float*)d_in[7];
    const float* b2  = (const float*)d_in[8];
    const float* w3  = (const float*)d_in[9];
    const float* bw3 = (const float*)d_in[10];
    const float* g3  = (const float*)d_in[11];
    const float* b3  = (const float*)d_in[12];
    float* out = (float*)d_out;

    float* cat    = (float*)d_ws;                     // [4][256][HW] 64MB
    float* h2     = cat + (long)4 * 256 * HW;         // [4][128][HW] 32MB
    float* sums1  = h2 + (long)4 * 128 * HW;          // 256
    float* sums2  = sums1 + 256;                      // 256
    float* sums3  = sums2 + 256;                      // 256
    float* mu     = sums3 + 256;                      // 128
    float* rstd   = mu + 128;                         // 128
    float* logits = rstd + 128;                       // [4][9][HW] 2.36MB
    float2* ab1   = (float2*)(logits + (long)4 * 9 * HW);   // [4][256]
    float2* ab2   = ab1 + 4 * 256;                          // [4][128]

    const long catN = 256L * HW, hN = 128L * HW, xN = 512L * HW;

    hipMemsetAsync(sums1, 0, 768 * sizeof(float), stream);
    hipMemsetAsync(logits, 0, (size_t)4 * 9 * HW * sizeof(float), stream);

    // scale1: 1x1 conv (bf16 MFMA, fused stats); xd RAW into cat ch 0..127
    conv1x1_mfma<512, 2, false><<<dim3(128, 1, 4), 256, 0, stream>>>(
        x, nullptr, w1, nullptr, cat, sums1, xN, catN);
    gn_coef_kernel<<<4, 256, 0, stream>>>(sums1, g1, b1, ab1, 1.f / 65536.f, 256, 2, 128);

    // cata (GN1 applied on load)
    cata_logits_kernel<<<dim3(16, 4, 8), 256, 0, stream>>>(cat, ab1, wc, logits);
    cata_wsum_kernel<<<dim3(16, 4, 8), 256, 0, stream>>>(cat, ab1, logits);

    // scale2: conv on concat (GN1/identity applied in staging); h2 RAW
    conv1x1_mfma<256, 2, true><<<dim3(128, 1, 4), 256, 0, stream>>>(
        cat, ab1, w2, bw2, h2, sums2, catN, hN);
    gn_coef_kernel<<<4, 256, 0, stream>>>(sums2, g2, b2, ab2, 1.f / 65536.f, 128, 2, 128);

    // scale3: conv (GN2 applied in staging); y3 RAW into out
    conv1x1_mfma<128, 4, true><<<dim3(128, 4, 4), 256, 0, stream>>>(
        h2, ab2, w3, bw3, out, sums3, hN, xN);
    gn_final_kernel<<<1, 128, 0, stream>>>(sums3, mu, rstd, 1.f / 262144.f);
    gn_final_apply_kernel<<<dim3(16, 512, 4), 256, 0, stream>>>(
        out, x, mu, rstd, g3, b3, xN, 16, 32);
}

// Round 5
// 232.293 us; speedup vs baseline: 1.9208x; 1.2848x over previous
//
#include <hip/hip_runtime.h>
#include <math.h>

#define HW 16384
#define W_ 128

typedef __bf16 bf16x8 __attribute__((ext_vector_type(8)));
typedef float f32x4 __attribute__((ext_vector_type(4)));

__device__ __forceinline__ ushort f2bf(float f) {
    uint u = __builtin_bit_cast(uint, f);
    u += 0x7FFFu + ((u >> 16) & 1u);   // round-to-nearest-even
    return (ushort)(u >> 16);
}
__device__ __forceinline__ float bf2f(ushort h) {
    return __builtin_bit_cast(float, (uint)h << 16);
}

union FragU { ushort u[8]; ushort4 h[2]; bf16x8 v; };

// ---------------------------------------------------------------------------
// 1x1 conv as bf16-MFMA GEMM + fused GN partial stats + optional fused
// input-GN-apply. Block tile OTILE o x 128 p, OTILE/32 waves (wave tile 64x64).
// A_s[o][k] pad 36; B_s[c][p] natural layout pad 132, transpose-on-read.
// Register-prefetch pipeline on staging loads. Optional bf16 output.
// ---------------------------------------------------------------------------
template<int IC, int OTILE, int LOG2CG, bool NORM_IN, bool BF16_OUT>
__global__ __launch_bounds__(OTILE * 2) void conv1x1_mfma(
    const float* __restrict__ in, const float2* __restrict__ ab,
    const float* __restrict__ w, const float* __restrict__ bias,
    void* __restrict__ out, float* __restrict__ sums,
    long in_nstride, long out_nstride)
{
    constexpr int NT = OTILE * 2;          // threads
    constexpr int BR = 1024 / NT;          // B-stage float4s per thread
    __shared__ ushort A_s[OTILE][36];
    __shared__ ushort B_s[32][132];
    __shared__ float gsum[32][2];
    const int tid = threadIdx.x;
    const int lane = tid & 63;
    const int wave = tid >> 6;
    const int woM = (wave >> 1) << 6;
    const int wpN = (wave & 1) << 6;
    const int lr = lane & 15;
    const int kg = (lane >> 4) << 2;
    const int n = blockIdx.z;
    const int obase = blockIdx.y * OTILE;
    const int pbase = blockIdx.x << 7;
    const float* inn = in + (long)n * in_nstride;

    if (tid < 32) { gsum[tid][0] = 0.f; gsum[tid][1] = 0.f; }

    f32x4 acc[4][4] = {};
    float4 areg[4], breg[BR];
    float2 abreg[BR];

    auto issue_loads = [&](int c0) {
#pragma unroll
        for (int r = 0; r < 4; ++r) {
            int idx4 = r * NT + tid;
            int o = idx4 >> 3, kq = idx4 & 7;
            areg[r] = *(const float4*)&w[(long)(obase + o) * IC + c0 + (kq << 2)];
        }
#pragma unroll
        for (int r = 0; r < BR; ++r) {
            int idx4 = r * NT + tid;
            int c = idx4 >> 5, p4 = (idx4 & 31) << 2;
            breg[r] = *(const float4*)&inn[(long)(c0 + c) * HW + pbase + p4];
            if (NORM_IN) abreg[r] = ab[(long)n * IC + c0 + c];
        }
    };
    auto write_lds = [&]() {
#pragma unroll
        for (int r = 0; r < 4; ++r) {
            int idx4 = r * NT + tid;
            int o = idx4 >> 3, kq = idx4 & 7;
            float4 v = areg[r];
            ushort4 h;
            h.x = f2bf(v.x); h.y = f2bf(v.y); h.z = f2bf(v.z); h.w = f2bf(v.w);
            *(ushort4*)&A_s[o][kq << 2] = h;
        }
#pragma unroll
        for (int r = 0; r < BR; ++r) {
            int idx4 = r * NT + tid;
            int c = idx4 >> 5, p4 = (idx4 & 31) << 2;
            float4 v = breg[r];
            if (NORM_IN) {
                float a = abreg[r].x, b = abreg[r].y;
                v.x = fmaxf(fmaf(v.x, a, b), 0.f);
                v.y = fmaxf(fmaf(v.y, a, b), 0.f);
                v.z = fmaxf(fmaf(v.z, a, b), 0.f);
                v.w = fmaxf(fmaf(v.w, a, b), 0.f);
            }
            ushort4 h;
            h.x = f2bf(v.x); h.y = f2bf(v.y); h.z = f2bf(v.z); h.w = f2bf(v.w);
            *(ushort4*)&B_s[c][p4] = h;
        }
    };

    issue_loads(0);
    constexpr int NS = IC / 32;
    for (int s = 0; s < NS; ++s) {
        write_lds();
        __syncthreads();
        if (s + 1 < NS) issue_loads((s + 1) << 5);

        FragU af[4];
#pragma unroll
        for (int mo = 0; mo < 4; ++mo) {
            const ushort* base = &A_s[woM + (mo << 4) + lr][0];
            af[mo].h[0] = *(const ushort4*)(base + kg);
            af[mo].h[1] = *(const ushort4*)(base + 16 + kg);
        }
#pragma unroll
        for (int po = 0; po < 4; ++po) {
            FragU bf_;
            int p = wpN + (po << 4) + lr;
#pragma unroll
            for (int j = 0; j < 4; ++j) {
                bf_.u[j]     = B_s[kg + j][p];
                bf_.u[4 + j] = B_s[16 + kg + j][p];
            }
#pragma unroll
            for (int mo = 0; mo < 4; ++mo)
                acc[mo][po] = __builtin_amdgcn_mfma_f32_16x16x32_bf16(
                    af[mo].v, bf_.v, acc[mo][po], 0, 0, 0);
        }
        __syncthreads();
    }

    if (bias) {
#pragma unroll
        for (int mo = 0; mo < 4; ++mo)
#pragma unroll
            for (int r = 0; r < 4; ++r) {
                float b = bias[obase + woM + (mo << 4) + kg + r];
#pragma unroll
                for (int po = 0; po < 4; ++po) acc[mo][po][r] += b;
            }
    }

#pragma unroll
    for (int mo = 0; mo < 4; ++mo) {
        int orow0 = obase + woM + (mo << 4) + kg;
#pragma unroll
        for (int po = 0; po < 4; ++po) {
            int p = pbase + wpN + (po << 4) + lr;
            if (BF16_OUT) {
                ushort* outn = (ushort*)out + (long)n * out_nstride;
#pragma unroll
                for (int r = 0; r < 4; ++r)
                    outn[(long)(orow0 + r) * HW + p] = f2bf(acc[mo][po][r]);
            } else {
                float* outn = (float*)out + (long)n * out_nstride;
#pragma unroll
                for (int r = 0; r < 4; ++r)
                    outn[(long)(orow0 + r) * HW + p] = acc[mo][po][r];
            }
        }
    }

    // fused GN partial stats: shfl-reduce 16-lane groups, leaders -> LDS -> global
#pragma unroll
    for (int mo = 0; mo < 4; ++mo) {
        float s = 0.f, ss = 0.f;
#pragma unroll
        for (int po = 0; po < 4; ++po)
#pragma unroll
            for (int r = 0; r < 4; ++r) {
                float v = acc[mo][po][r];
                s += v; ss += v * v;
            }
#pragma unroll
        for (int m = 8; m >= 1; m >>= 1) {
            s  += __shfl_xor(s, m, 64);
            ss += __shfl_xor(ss, m, 64);
        }
        if (lr == 0) {
            int gt = (woM + (mo << 4) + kg) >> LOG2CG;
            atomicAdd(&gsum[gt][0], s);
            atomicAdd(&gsum[gt][1], ss);
        }
    }
    __syncthreads();
    if (tid < (OTILE >> LOG2CG)) {
        int g = (obase >> LOG2CG) + tid;
        atomicAdd(&sums[2 * (n * 32 + g)],     gsum[tid][0]);
        atomicAdd(&sums[2 * (n * 32 + g) + 1], gsum[tid][1]);
    }
}

// ---------------------------------------------------------------------------
__global__ void gn_coef_kernel(const float* __restrict__ sums,
                               const float* __restrict__ gamma,
                               const float* __restrict__ beta,
                               float2* __restrict__ ab,
                               float cinv, int C, int log2cg, int norm_c)
{
    int n = blockIdx.x;
    for (int c = threadIdx.x; c < C; c += blockDim.x) {
        float a = 1.f, b = 0.f;
        if (c < norm_c) {
            int g = c >> log2cg;
            float m = sums[2 * (n * 32 + g)] * cinv;
            float var = sums[2 * (n * 32 + g) + 1] * cinv - m * m;
            float r = rsqrtf(var + 1e-5f);
            a = r * gamma[c];
            b = beta[c] - m * a;
        }
        ab[(long)n * C + c] = make_float2(a, b);
    }
}

__global__ void gn_final_kernel(const float* __restrict__ sums,
                                float* __restrict__ mu, float* __restrict__ rstd,
                                float cinv)
{
    int i = threadIdx.x;
    if (i < 128) {
        float m = sums[2 * i] * cinv;
        float var = sums[2 * i + 1] * cinv - m * m;
        mu[i] = m;
        rstd[i] = rsqrtf(var + 1e-5f);
    }
}

// final: out = relu((y3-mu)*rstd*g + b) + x, y3 is bf16
__global__ __launch_bounds__(256) void gn_final_apply_kernel(
    const ushort* __restrict__ y, const float* __restrict__ x,
    float* __restrict__ out,
    const float* __restrict__ mu, const float* __restrict__ rstd,
    const float* __restrict__ gamma, const float* __restrict__ beta)
{
    const int n = blockIdx.z, c = blockIdx.y;
    const int ng = n * 32 + (c >> 4);
    const float a = rstd[ng] * gamma[c];
    const float b = beta[c] - mu[ng] * a;
    long off = (long)n * 512 * HW + (long)c * HW + (blockIdx.x << 10) + (threadIdx.x << 2);
    ushort4 u = *(const ushort4*)&y[off];
    float4 xv = *(const float4*)&x[off];
    float4 v;
    v.x = fmaxf(fmaf(bf2f(u.x), a, b), 0.f) + xv.x;
    v.y = fmaxf(fmaf(bf2f(u.y), a, b), 0.f) + xv.y;
    v.z = fmaxf(fmaf(bf2f(u.z), a, b), 0.f) + xv.z;
    v.w = fmaxf(fmaf(bf2f(u.w), a, b), 0.f) + xv.w;
    *(float4*)&out[off] = v;
}

// ---------------------------------------------------------------------------
// cata pass 1: 3x3 conv -> 9 logits. Double-buffered halo with register
// prefetch; weights padded to 12 floats (float4 LDS reads). 16-ch chunks,
// tile 8 rows x 128 cols, 4 px/thread, atomics into logits.
// ---------------------------------------------------------------------------
#define RT 8
__global__ __launch_bounds__(256) void cata_logits_kernel(
    const float* __restrict__ xd, const float2* __restrict__ ab,
    const float* __restrict__ wc, float* __restrict__ logits)
{
    __shared__ __align__(16) float wcs[9 * 16 * 12];   // 6912 B
    __shared__ float xs[2][RT + 2][130];               // 10400 B
    const int tid = threadIdx.x;
    const int r0 = blockIdx.x * RT;
    const int n = blockIdx.y;
    const int c0 = blockIdx.z << 4;
    const int qq = tid >> 7;
    const int w = tid & 127;
    for (int i = tid; i < 9 * 16 * 9; i += 256) {
        int k = i / 144, rem = i % 144, cc = rem / 9, t = rem % 9;
        wcs[(k * 16 + cc) * 12 + t] = wc[k * 1152 + (c0 + cc) * 9 + t];
    }
    const float* xn = xd + (long)n * 256 * HW;
    float pf[6];
    float2 abn;
    auto issue = [&](int cc) {
        const float* xc = xn + (long)(c0 + cc) * HW;
        abn = ab[(long)n * 256 + c0 + cc];
#pragma unroll
        for (int r = 0; r < 6; ++r) {
            int idx = (r << 8) + tid;
            float v = 0.f;
            if (idx < 1300) {
                int rr = idx / 130, cl = idx - rr * 130;
                int gr = r0 - 1 + rr, gc = cl - 1;
                if ((unsigned)gr < 128u && (unsigned)gc < 128u) v = xc[gr * W_ + gc];
            }
            pf[r] = v;
        }
    };
    auto commit = [&](int buf) {
#pragma unroll
        for (int r = 0; r < 6; ++r) {
            int idx = (r << 8) + tid;
            if (idx < 1300) {
                int rr = idx / 130, cl = idx - rr * 130;
                xs[buf][rr][cl] = fmaxf(fmaf(pf[r], abn.x, abn.y), 0.f);
            }
        }
    };

    issue(0);
    float lg[4][9] = {};
    for (int cc = 0; cc < 16; ++cc) {
        int buf = cc & 1;
        commit(buf);
        __syncthreads();
        if (cc < 15) issue(cc + 1);
        float nb[6][3];
#pragma unroll
        for (int rr = 0; rr < 6; ++rr)
#pragma unroll
            for (int dj = 0; dj < 3; ++dj)
                nb[rr][dj] = xs[buf][(qq << 2) + rr][w + dj];
#pragma unroll
        for (int k = 0; k < 9; ++k) {
            const float* wp = &wcs[(k * 16 + cc) * 12];
            float4 wa = *(const float4*)wp;
            float4 wb = *(const float4*)(wp + 4);
            float w8 = wp[8];
#pragma unroll
            for (int i = 0; i < 4; ++i) {
                float s = lg[i][k];
                s = fmaf(wa.x, nb[i][0], s);     s = fmaf(wa.y, nb[i][1], s);
                s = fmaf(wa.z, nb[i][2], s);     s = fmaf(wa.w, nb[i + 1][0], s);
                s = fmaf(wb.x, nb[i + 1][1], s); s = fmaf(wb.y, nb[i + 1][2], s);
                s = fmaf(wb.z, nb[i + 2][0], s); s = fmaf(wb.w, nb[i + 2][1], s);
                s = fmaf(w8,   nb[i + 2][2], s);
                lg[i][k] = s;
            }
        }
    }
    float* lgn = logits + (long)n * 9 * HW;
#pragma unroll
    for (int i = 0; i < 4; ++i) {
        int p = (r0 + (qq << 2) + i) * W_ + w;
#pragma unroll
        for (int k = 0; k < 9; ++k)
            atomicAdd(&lgn[(long)k * HW + p], lg[i][k]);
    }
}

// ---------------------------------------------------------------------------
// cata pass 2: softmax over 9 logits + weighted 3x3 sum, same tiling +
// double-buffered prefetch. out1 -> cat channels 128..255.
// ---------------------------------------------------------------------------
__global__ __launch_bounds__(256) void cata_wsum_kernel(
    float* __restrict__ cat, const float2* __restrict__ ab,
    const float* __restrict__ logits)
{
    __shared__ float xs[2][RT + 2][130];
    const int tid = threadIdx.x;
    const int r0 = blockIdx.x * RT;
    const int n = blockIdx.y;
    const int c0 = blockIdx.z << 4;
    const int qq = tid >> 7;
    const int w = tid & 127;
    const float* lgn = logits + (long)n * 9 * HW;
    float filt[4][9];
#pragma unroll
    for (int i = 0; i < 4; ++i) {
        int p = (r0 + (qq << 2) + i) * W_ + w;
        float v[9], m = -1e30f;
#pragma unroll
        for (int k = 0; k < 9; ++k) {
            v[k] = lgn[(long)k * HW + p];
            m = fmaxf(m, v[k]);
        }
        float s = 0.f;
#pragma unroll
        for (int k = 0; k < 9; ++k) { v[k] = __expf(v[k] - m); s += v[k]; }
        float inv = 1.f / s;
#pragma unroll
        for (int k = 0; k < 9; ++k) filt[i][k] = v[k] * inv;
    }
    const float* xn = cat + (long)n * 256 * HW;
    float* o1 = cat + (long)n * 256 * HW + 128L * HW;
    float pf[6];
    float2 abn;
    auto issue = [&](int cc) {
        const float* xc = xn + (long)(c0 + cc) * HW;
        abn = ab[(long)n * 256 + c0 + cc];
#pragma unroll
        for (int r = 0; r < 6; ++r) {
            int idx = (r << 8) + tid;
            float v = 0.f;
            if (idx < 1300) {
                int rr = idx / 130, cl = idx - rr * 130;
                int gr = r0 - 1 + rr, gc = cl - 1;
                if ((unsigned)gr < 128u && (unsigned)gc < 128u) v = xc[gr * W_ + gc];
            }
            pf[r] = v;
        }
    };
    auto commit = [&](int buf) {
#pragma unroll
        for (int r = 0; r < 6; ++r) {
            int idx = (r << 8) + tid;
            if (idx < 1300) {
                int rr = idx / 130, cl = idx - rr * 130;
                xs[buf][rr][cl] = fmaxf(fmaf(pf[r], abn.x, abn.y), 0.f);
            }
        }
    };

    issue(0);
    for (int cc = 0; cc < 16; ++cc) {
        int buf = cc & 1;
        commit(buf);
        __syncthreads();
        if (cc < 15) issue(cc + 1);
        float nb[6][3];
#pragma unroll
        for (int rr = 0; rr < 6; ++rr)
#pragma unroll
            for (int dj = 0; dj < 3; ++dj)
                nb[rr][dj] = xs[buf][(qq << 2) + rr][w + dj];
#pragma unroll
        for (int i = 0; i < 4; ++i) {
            float s = 0.f;
#pragma unroll
            for (int di = 0; di < 3; ++di)
#pragma unroll
                for (int dj = 0; dj < 3; ++dj)
                    s = fmaf(filt[i][di * 3 + dj], nb[i + di][dj], s);
            o1[(long)(c0 + cc) * HW + (r0 + (qq << 2) + i) * W_ + w] = s;
        }
    }
}

// ---------------------------------------------------------------------------
extern "C" void kernel_launch(void* const* d_in, const int* in_sizes, int n_in,
                              void* d_out, int out_size, void* d_ws, size_t ws_size,
                              hipStream_t stream)
{
    const float* x   = (const float*)d_in[0];
    const float* w1  = (const float*)d_in[1];
    const float* g1  = (const float*)d_in[2];
    const float* b1  = (const float*)d_in[3];
    const float* wc  = (const float*)d_in[4];
    const float* w2  = (const float*)d_in[5];
    const float* bw2 = (const float*)d_in[6];
    const float* g2  = (const float*)d_in[7];
    const float* b2  = (const float*)d_in[8];
    const float* w3  = (const float*)d_in[9];
    const float* bw3 = (const float*)d_in[10];
    const float* g3  = (const float*)d_in[11];
    const float* b3  = (const float*)d_in[12];
    float* out = (float*)d_out;

    float* cat    = (float*)d_ws;                     // [4][256][HW] fp32 64MB
    float* h2     = cat + (long)4 * 256 * HW;         // [4][128][HW] fp32 32MB
    float* sums1  = h2 + (long)4 * 128 * HW;          // 256
    float* sums2  = sums1 + 256;                      // 256
    float* sums3  = sums2 + 256;                      // 256
    float* mu     = sums3 + 256;                      // 128
    float* rstd   = mu + 128;                         // 128
    float* logits = rstd + 128;                       // [4][9][HW] 2.36MB
    float2* ab1   = (float2*)(logits + (long)4 * 9 * HW);   // [4][256]
    float2* ab2   = ab1 + 4 * 256;                          // [4][128]
    ushort* y3    = (ushort*)(ab2 + 4 * 128);               // [4][512][HW] bf16 64MB

    const long catN = 256L * HW, hN = 128L * HW, xN = 512L * HW;

    hipMemsetAsync(sums1, 0, 768 * sizeof(float), stream);
    hipMemsetAsync(logits, 0, (size_t)4 * 9 * HW * sizeof(float), stream);

    // scale1: 1x1 conv (bf16 MFMA, fused stats); xd RAW fp32 into cat ch 0..127
    conv1x1_mfma<512, 128, 2, false, false><<<dim3(128, 1, 4), 256, 0, stream>>>(
        x, nullptr, w1, nullptr, cat, sums1, xN, catN);
    gn_coef_kernel<<<4, 256, 0, stream>>>(sums1, g1, b1, ab1, 1.f / 65536.f, 256, 2, 128);

    // cata (GN1 applied on load)
    cata_logits_kernel<<<dim3(16, 4, 8), 256, 0, stream>>>(cat, ab1, wc, logits);
    cata_wsum_kernel<<<dim3(16, 4, 8), 256, 0, stream>>>(cat, ab1, logits);

    // scale2: conv on concat (GN1/identity applied in staging); h2 RAW fp32
    conv1x1_mfma<256, 128, 2, true, false><<<dim3(128, 1, 4), 256, 0, stream>>>(
        cat, ab1, w2, bw2, h2, sums2, catN, hN);
    gn_coef_kernel<<<4, 256, 0, stream>>>(sums2, g2, b2, ab2, 1.f / 65536.f, 128, 2, 128);

    // scale3: conv 256o-tile (GN2 applied in staging); y3 bf16
    conv1x1_mfma<128, 256, 4, true, true><<<dim3(128, 2, 4), 512, 0, stream>>>(
        h2, ab2, w3, bw3, y3, sums3, hN, xN);
    gn_final_kernel<<<1, 128, 0, stream>>>(sums3, mu, rstd, 1.f / 262144.f);
    gn_final_apply_kernel<<<dim3(16, 512, 4), 256, 0, stream>>>(
        y3, x, out, mu, rstd, g3, b3);
}